// Round 1
// baseline (1690.213 us; speedup 1.0000x reference)
//
#include <hip/hip_runtime.h>

#define NN 100000
#define NE 640000
#define D 128
#define HH 256
#define TD 384

typedef __bf16 bf16x8 __attribute__((ext_vector_type(8)));
typedef float f32x4 __attribute__((ext_vector_type(4)));

__device__ __forceinline__ unsigned short f2bf(float f) {
    unsigned u = __builtin_bit_cast(unsigned, f);
    u += 0x7FFFu + ((u >> 16) & 1u);
    return (unsigned short)(u >> 16);
}

__global__ void cvt_bf16_kernel(const float* __restrict__ src,
                                unsigned short* __restrict__ dst, int n) {
    int i = blockIdx.x * 256 + threadIdx.x;
    if (i < n) dst[i] = f2bf(src[i]);
}

// ---------------- fused edge MLP (both directions) + scatter ----------------
// block = 256 threads (4 waves), 32 edges -> 64 MFMA rows (rows 0-31 dir0, 32-63 dir1)
__global__ __launch_bounds__(256, 2) void edge_mlp_kernel(
    const float* __restrict__ ns, const float* __restrict__ ef,
    const int* __restrict__ fidx, const int* __restrict__ tidx,
    const unsigned short* __restrict__ w1b, const float* __restrict__ b1,
    const unsigned short* __restrict__ w2b, const float* __restrict__ b2,
    const unsigned short* __restrict__ w3b, const float* __restrict__ b3,
    float* __restrict__ agg)
{
    __shared__ __align__(16) unsigned short chunks[96 * 128]; // (part*32+edge)*128, part: 0=F 1=T 2=E
    __shared__ __align__(16) unsigned short hbuf[64 * 256];
    __shared__ int sF[32], sT[32];

    const int tid = threadIdx.x;
    const int e0 = blockIdx.x * 32;
    if (tid < 32) { sF[tid] = fidx[e0 + tid]; sT[tid] = tidx[e0 + tid]; }
    __syncthreads();

    // stage 96 chunks of 128 f32 -> bf16, XOR-swizzled per 16B slot
    {
        const int kk0 = (tid & 7) * 16;
        for (int c = tid >> 3; c < 96; c += 32) {
            const int edge = c & 31;
            const int part = c >> 5;
            const float* src = (part == 0) ? ns + (size_t)sF[edge] * D
                             : (part == 1) ? ns + (size_t)sT[edge] * D
                                           : ef + (size_t)(e0 + edge) * D;
            unsigned short* cb = chunks + c * 128;
            #pragma unroll
            for (int g = 0; g < 2; g++) {
                float4 a = *(const float4*)(src + kk0 + g * 8);
                float4 b = *(const float4*)(src + kk0 + g * 8 + 4);
                uint4 pk;
                pk.x = f2bf(a.x) | ((unsigned)f2bf(a.y) << 16);
                pk.y = f2bf(a.z) | ((unsigned)f2bf(a.w) << 16);
                pk.z = f2bf(b.x) | ((unsigned)f2bf(b.y) << 16);
                pk.w = f2bf(b.z) | ((unsigned)f2bf(b.w) << 16);
                int sw = (kk0 + g * 8) ^ ((edge & 7) << 3);
                *(uint4*)(cb + sw) = pk;
            }
        }
    }
    __syncthreads();

    const int w  = tid >> 6;
    const int l  = tid & 63;
    const int lr = l & 15;
    const int lk = l >> 4;

    // ---- layer 1: [64,384] x w1^T -> [64,256], wave w owns cols w*64..w*64+63
    f32x4 acc1[4][4];
    #pragma unroll
    for (int mt = 0; mt < 4; mt++)
        #pragma unroll
        for (int ct = 0; ct < 4; ct++) acc1[mt][ct] = (f32x4){0.f, 0.f, 0.f, 0.f};

    for (int kc = 0; kc < 12; kc++) {
        const int gk = kc * 32;
        const int c128 = gk >> 7;
        const int kk = (gk & 127) + lk * 8;
        bf16x8 af[4];
        #pragma unroll
        for (int mt = 0; mt < 4; mt++) {
            int edge = ((mt & 1) << 4) + lr;
            int dir = mt >> 1;
            int part = dir ? (c128 == 0 ? 1 : (c128 == 1 ? 0 : 2)) : c128;
            int idx = (part * 32 + edge) * 128 + (kk ^ ((edge & 7) << 3));
            af[mt] = *(const bf16x8*)(chunks + idx);
        }
        #pragma unroll
        for (int ct = 0; ct < 4; ct++) {
            int col = (w * 4 + ct) * 16 + lr;
            bf16x8 bfr = *(const bf16x8*)(w1b + col * TD + gk + lk * 8);
            #pragma unroll
            for (int mt = 0; mt < 4; mt++)
                acc1[mt][ct] = __builtin_amdgcn_mfma_f32_16x16x32_bf16(af[mt], bfr, acc1[mt][ct], 0, 0, 0);
        }
    }
    // bias + relu -> hbuf (swizzled)
    #pragma unroll
    for (int ct = 0; ct < 4; ct++) {
        int col = (w * 4 + ct) * 16 + lr;
        float bias = b1[col];
        #pragma unroll
        for (int mt = 0; mt < 4; mt++)
            #pragma unroll
            for (int j = 0; j < 4; j++) {
                int row = mt * 16 + lk * 4 + j;
                float v = acc1[mt][ct][j] + bias;
                v = v > 0.f ? v : 0.f;
                hbuf[row * 256 + (col ^ ((row & 7) << 3))] = f2bf(v);
            }
    }
    __syncthreads();

    // ---- layer 2: [64,256] x w2^T -> [64,256]
    f32x4 acc2[4][4];
    #pragma unroll
    for (int mt = 0; mt < 4; mt++)
        #pragma unroll
        for (int ct = 0; ct < 4; ct++) acc2[mt][ct] = (f32x4){0.f, 0.f, 0.f, 0.f};

    for (int kc = 0; kc < 8; kc++) {
        const int k = kc * 32 + lk * 8;
        bf16x8 af[4];
        #pragma unroll
        for (int mt = 0; mt < 4; mt++) {
            int row = mt * 16 + lr;
            af[mt] = *(const bf16x8*)(hbuf + row * 256 + (k ^ ((row & 7) << 3)));
        }
        #pragma unroll
        for (int ct = 0; ct < 4; ct++) {
            int col = (w * 4 + ct) * 16 + lr;
            bf16x8 bfr = *(const bf16x8*)(w2b + col * 256 + k);
            #pragma unroll
            for (int mt = 0; mt < 4; mt++)
                acc2[mt][ct] = __builtin_amdgcn_mfma_f32_16x16x32_bf16(af[mt], bfr, acc2[mt][ct], 0, 0, 0);
        }
    }
    __syncthreads();   // everyone done reading h1
    #pragma unroll
    for (int ct = 0; ct < 4; ct++) {
        int col = (w * 4 + ct) * 16 + lr;
        float bias = b2[col];
        #pragma unroll
        for (int mt = 0; mt < 4; mt++)
            #pragma unroll
            for (int j = 0; j < 4; j++) {
                int row = mt * 16 + lk * 4 + j;
                float v = acc2[mt][ct][j] + bias;
                v = v > 0.f ? v : 0.f;
                hbuf[row * 256 + (col ^ ((row & 7) << 3))] = f2bf(v);
            }
    }
    __syncthreads();

    // ---- layer 3: [64,256] x w3^T -> [64,128], wave w owns cols w*32..w*32+31
    f32x4 acc3[4][2];
    #pragma unroll
    for (int mt = 0; mt < 4; mt++) { acc3[mt][0] = (f32x4){0.f,0.f,0.f,0.f}; acc3[mt][1] = (f32x4){0.f,0.f,0.f,0.f}; }

    for (int kc = 0; kc < 8; kc++) {
        const int k = kc * 32 + lk * 8;
        bf16x8 af[4];
        #pragma unroll
        for (int mt = 0; mt < 4; mt++) {
            int row = mt * 16 + lr;
            af[mt] = *(const bf16x8*)(hbuf + row * 256 + (k ^ ((row & 7) << 3)));
        }
        #pragma unroll
        for (int ct = 0; ct < 2; ct++) {
            int col = (w * 2 + ct) * 16 + lr;
            bf16x8 bfr = *(const bf16x8*)(w3b + col * 256 + k);
            #pragma unroll
            for (int mt = 0; mt < 4; mt++)
                acc3[mt][ct] = __builtin_amdgcn_mfma_f32_16x16x32_bf16(af[mt], bfr, acc3[mt][ct], 0, 0, 0);
        }
    }

    // bias + atomic scatter: dir0 rows -> to_idx, dir1 rows -> from_idx
    #pragma unroll
    for (int ct = 0; ct < 2; ct++) {
        int d = (w * 2 + ct) * 16 + lr;
        float bias = b3[d];
        #pragma unroll
        for (int mt = 0; mt < 4; mt++)
            #pragma unroll
            for (int j = 0; j < 4; j++) {
                int edge = ((mt & 1) << 4) + lk * 4 + j;
                int node = (mt >> 1) ? sF[edge] : sT[edge];
                atomicAdd(agg + (size_t)node * D + d, acc3[mt][ct][j] + bias);
            }
    }
}

// ---------------- GRU: out = GRU(x, h) -----------------
// block = 256 threads (4 waves), 32 node rows; wave w owns d-cols w*32..w*32+31
__global__ __launch_bounds__(256, 2) void gru_kernel(
    const float* __restrict__ x, const float* __restrict__ h,
    const unsigned short* __restrict__ wihb, const unsigned short* __restrict__ whhb,
    const float* __restrict__ bih, const float* __restrict__ bhh,
    float* __restrict__ out)
{
    __shared__ __align__(16) unsigned short xb[32 * 128];
    __shared__ __align__(16) unsigned short hb[32 * 128];
    const int tid = threadIdx.x;
    const size_t r0 = (size_t)blockIdx.x * 32;

    {
        const int row = tid >> 3;
        const int kk0 = (tid & 7) * 16;
        const float* sx = x + (r0 + row) * D + kk0;
        const float* sh = h + (r0 + row) * D + kk0;
        #pragma unroll
        for (int g = 0; g < 2; g++) {
            float4 a = *(const float4*)(sx + g * 8);
            float4 b = *(const float4*)(sx + g * 8 + 4);
            uint4 pk;
            pk.x = f2bf(a.x) | ((unsigned)f2bf(a.y) << 16);
            pk.y = f2bf(a.z) | ((unsigned)f2bf(a.w) << 16);
            pk.z = f2bf(b.x) | ((unsigned)f2bf(b.y) << 16);
            pk.w = f2bf(b.z) | ((unsigned)f2bf(b.w) << 16);
            int sw = (kk0 + g * 8) ^ ((row & 7) << 3);
            *(uint4*)(xb + row * 128 + sw) = pk;
            a = *(const float4*)(sh + g * 8);
            b = *(const float4*)(sh + g * 8 + 4);
            pk.x = f2bf(a.x) | ((unsigned)f2bf(a.y) << 16);
            pk.y = f2bf(a.z) | ((unsigned)f2bf(a.w) << 16);
            pk.z = f2bf(b.x) | ((unsigned)f2bf(b.y) << 16);
            pk.w = f2bf(b.z) | ((unsigned)f2bf(b.w) << 16);
            *(uint4*)(hb + row * 128 + sw) = pk;
        }
    }
    __syncthreads();

    const int w = tid >> 6, l = tid & 63, lr = l & 15, lk = l >> 4;

    f32x4 agi[2][3][2], agh[2][3][2];   // [mtile][gate r/z/n][local d-tile]
    #pragma unroll
    for (int mt = 0; mt < 2; mt++)
        #pragma unroll
        for (int g = 0; g < 3; g++)
            #pragma unroll
            for (int t = 0; t < 2; t++) {
                agi[mt][g][t] = (f32x4){0.f,0.f,0.f,0.f};
                agh[mt][g][t] = (f32x4){0.f,0.f,0.f,0.f};
            }

    for (int kc = 0; kc < 4; kc++) {
        const int k = kc * 32 + lk * 8;
        bf16x8 ax[2], ah[2];
        #pragma unroll
        for (int mt = 0; mt < 2; mt++) {
            int row = mt * 16 + lr;
            int idx = row * 128 + (k ^ ((row & 7) << 3));
            ax[mt] = *(const bf16x8*)(xb + idx);
            ah[mt] = *(const bf16x8*)(hb + idx);
        }
        #pragma unroll
        for (int g = 0; g < 3; g++)
            #pragma unroll
            for (int t = 0; t < 2; t++) {
                int col = g * 128 + (w * 2 + t) * 16 + lr;
                bf16x8 bi = *(const bf16x8*)(wihb + col * 128 + k);
                bf16x8 bh = *(const bf16x8*)(whhb + col * 128 + k);
                #pragma unroll
                for (int mt = 0; mt < 2; mt++) {
                    agi[mt][g][t] = __builtin_amdgcn_mfma_f32_16x16x32_bf16(ax[mt], bi, agi[mt][g][t], 0, 0, 0);
                    agh[mt][g][t] = __builtin_amdgcn_mfma_f32_16x16x32_bf16(ah[mt], bh, agh[mt][g][t], 0, 0, 0);
                }
            }
    }

    #pragma unroll
    for (int t = 0; t < 2; t++) {
        const int d = (w * 2 + t) * 16 + lr;
        const float bir = bih[d], biz = bih[D + d], bin_ = bih[2 * D + d];
        const float bhr = bhh[d], bhz = bhh[D + d], bhn = bhh[2 * D + d];
        #pragma unroll
        for (int mt = 0; mt < 2; mt++)
            #pragma unroll
            for (int j = 0; j < 4; j++) {
                size_t row = r0 + mt * 16 + lk * 4 + j;
                float hv = h[row * D + d];
                float rr = agi[mt][0][t][j] + bir + agh[mt][0][t][j] + bhr;
                float zz = agi[mt][1][t][j] + biz + agh[mt][1][t][j] + bhz;
                float ni = agi[mt][2][t][j] + bin_;
                float nh = agh[mt][2][t][j] + bhn;
                float r_ = 1.f / (1.f + __expf(-rr));
                float z_ = 1.f / (1.f + __expf(-zz));
                float n_ = tanhf(ni + r_ * nh);
                out[row * D + d] = (1.f - z_) * n_ + z_ * hv;
            }
    }
}

extern "C" void kernel_launch(void* const* d_in, const int* in_sizes, int n_in,
                              void* d_out, int out_size, void* d_ws, size_t ws_size,
                              hipStream_t stream)
{
    const float* ns = (const float*)d_in[0];
    const float* ef = (const float*)d_in[1];
    const int*   fidx = (const int*)d_in[2];
    const int*   tidx = (const int*)d_in[3];
    const float* w1 = (const float*)d_in[5];
    const float* b1 = (const float*)d_in[6];
    const float* w2 = (const float*)d_in[7];
    const float* b2 = (const float*)d_in[8];
    const float* w3 = (const float*)d_in[9];
    const float* b3 = (const float*)d_in[10];
    const float* gwih_f[3] = {(const float*)d_in[11], (const float*)d_in[15], (const float*)d_in[19]};
    const float* gwhh_f[3] = {(const float*)d_in[12], (const float*)d_in[16], (const float*)d_in[20]};
    const float* gbih[3]   = {(const float*)d_in[13], (const float*)d_in[17], (const float*)d_in[21]};
    const float* gbhh[3]   = {(const float*)d_in[14], (const float*)d_in[18], (const float*)d_in[22]};

    char* ws = (char*)d_ws;
    float* agg = (float*)ws;                                   // N*D f32
    float* s1  = (float*)(ws + (size_t)NN * D * 4);            // N*D f32
    unsigned short* w1b = (unsigned short*)(ws + (size_t)2 * NN * D * 4);
    unsigned short* w2b = w1b + 256 * 384;
    unsigned short* w3b = w2b + 256 * 256;
    unsigned short* gwih[3];
    unsigned short* gwhh[3];
    {
        unsigned short* p = w3b + 128 * 256;
        for (int i = 0; i < 3; i++) { gwih[i] = p; p += 384 * 128; gwhh[i] = p; p += 384 * 128; }
    }

    auto cvt = [&](const float* s, unsigned short* dst, int n) {
        cvt_bf16_kernel<<<(n + 255) / 256, 256, 0, stream>>>(s, dst, n);
    };
    cvt(w1, w1b, 256 * 384);
    cvt(w2, w2b, 256 * 256);
    cvt(w3, w3b, 128 * 256);
    for (int i = 0; i < 3; i++) { cvt(gwih_f[i], gwih[i], 384 * 128); cvt(gwhh_f[i], gwhh[i], 384 * 128); }

    hipMemsetAsync(agg, 0, (size_t)NN * D * 4, stream);

    edge_mlp_kernel<<<NE / 32, 256, 0, stream>>>(ns, ef, fidx, tidx, w1b, b1, w2b, b2, w3b, b3, agg);

    float* s2 = (float*)d_out;
    gru_kernel<<<NN / 32, 256, 0, stream>>>(ns,  agg, gwih[0], gwhh[0], gbih[0], gbhh[0], s1);
    gru_kernel<<<NN / 32, 256, 0, stream>>>(agg, s1,  gwih[1], gwhh[1], gbih[1], gbhh[1], s2);
    gru_kernel<<<NN / 32, 256, 0, stream>>>(s1,  s2,  gwih[2], gwhh[2], gbih[2], gbhh[2], (float*)d_out);
}